// Round 3
// baseline (746.548 us; speedup 1.0000x reference)
//
#include <hip/hip_runtime.h>
#include <stdint.h>

// Problem dims
#define T_TOT 32768   // B*S
#define H_DIM 1024
#define A_DIM 32
#define E_NUM 8
#define ED_DIM 256
#define RH_DIM 128
#define NBIG 2560     // 8*256 experts + 256 shared + 128 router + 128 value
#define K2 2304       // 8*256 + 256 (expert+shared h1 -> action)
#define CHUNK 8192
#define NCHUNK 4

typedef float f32x4 __attribute__((ext_vector_type(4)));
typedef short bf16x8 __attribute__((ext_vector_type(8)));
typedef unsigned short u16;
typedef u16 u16x8 __attribute__((ext_vector_type(8)));

typedef uint32_t __attribute__((address_space(1))) as1_u32;
typedef uint32_t __attribute__((address_space(3))) as3_u32;

__device__ __forceinline__ u16 f2bf(float f) {
    union { float f; uint32_t u; } v; v.f = f;
    return (u16)((v.u + 0x7FFFu + ((v.u >> 16) & 1u)) >> 16);  // RNE
}
__device__ __forceinline__ float bf2f(u16 h) {
    union { uint32_t u; float f; } v; v.u = ((uint32_t)h) << 16;
    return v.f;
}
__device__ __forceinline__ float gelu_erf(float x) {
    return 0.5f * x * (1.0f + erff(x * 0.70710678118654752f));
}
__device__ __forceinline__ void gload_lds16(const void* g, void* lds) {
    __builtin_amdgcn_global_load_lds((const as1_u32*)(uintptr_t)g,
                                     (as3_u32*)(uintptr_t)lds, 16, 0, 0);
}

// ---------------- setup kernels ----------------

// state_rep fp32 -> bf16 (one chunk)
__global__ void k_convert_x(const float* __restrict__ x, u16* __restrict__ xb, int n4) {
    int i = blockIdx.x * blockDim.x + threadIdx.x;
    if (i >= n4) return;
    float4 v = ((const float4*)x)[i];
    u16x8 dummy; (void)dummy;
    ushort4 o;
    o.x = f2bf(v.x); o.y = f2bf(v.y); o.z = f2bf(v.z); o.w = f2bf(v.w);
    ((ushort4*)xb)[i] = o;
}

// pack big W^T [NBIG][K=1024] bf16 + concatenated bias (fp32)
__global__ void k_pack_w(const float* __restrict__ ew1, const float* __restrict__ sw1,
                         const float* __restrict__ rw1, const float* __restrict__ vw1,
                         const float* __restrict__ eb1, const float* __restrict__ sb1,
                         const float* __restrict__ rb1, const float* __restrict__ vb1,
                         u16* __restrict__ wbf, float* __restrict__ biascat) {
    int t = blockIdx.x * blockDim.x + threadIdx.x;
    if (t >= NBIG * H_DIM) return;
    int n = t >> 10, k = t & 1023;
    float v;
    if (n < 2048)      v = ew1[(size_t)(((n >> 8) * H_DIM) + k) * ED_DIM + (n & 255)];
    else if (n < 2304) v = sw1[(size_t)k * ED_DIM + (n - 2048)];
    else if (n < 2432) v = rw1[(size_t)k * RH_DIM + (n - 2304)];
    else               v = vw1[(size_t)k * RH_DIM + (n - 2432)];
    wbf[t] = f2bf(v);
    if (k == 0) {
        float b;
        if (n < 2048)      b = eb1[(n >> 8) * ED_DIM + (n & 255)];
        else if (n < 2304) b = sb1[n - 2048];
        else if (n < 2432) b = rb1[n - 2304];
        else               b = vb1[n - 2432];
        biascat[n] = b;
    }
}

// pack second-layer weights transposed: W2T [32][2304] bf16 (expert | shared)
__global__ void k_pack_w2t(const float* __restrict__ ew2, const float* __restrict__ sw2,
                           u16* __restrict__ w2t) {
    int t = blockIdx.x * blockDim.x + threadIdx.x;
    if (t >= A_DIM * K2) return;
    int a = t / K2, d = t - a * K2;
    float v = (d < 2048) ? ew2[(size_t)d * A_DIM + a] : sw2[(size_t)(d - 2048) * A_DIM + a];
    w2t[t] = f2bf(v);
}

// candidate_actions = base_action * linspace(0.8,1.2,8)
__global__ void k_cand(const float* __restrict__ base, float* __restrict__ outp) {
    int i = blockIdx.x * blockDim.x + threadIdx.x;
    if (i >= T_TOT * E_NUM * A_DIM) return;
    int a = i & 31, e = (i >> 5) & 7, t = i >> 8;
    outp[i] = base[(size_t)t * A_DIM + a] * (0.8f + 0.4f * (float)e / 7.0f);
}

// ---------------- GEMM1: X[8192x1024] @ Wbig -> H1[8192x2560] (act applied, bf16) ----------------

__launch_bounds__(256, 2)
__global__ void k_gemm1(const u16* __restrict__ xb, const u16* __restrict__ wbf,
                        const float* __restrict__ biascat, u16* __restrict__ h1) {
    __shared__ u16 As[128 * 64];
    __shared__ u16 Bs[128 * 64];
    const int tid = threadIdx.x;
    const int wid = tid >> 6;
    const int lane = tid & 63;
    const int m0 = blockIdx.y * 128;
    const int n0 = blockIdx.x * 128;
    const int wr = wid >> 1, wc = wid & 1;

    f32x4 acc[4][4];
#pragma unroll
    for (int m = 0; m < 4; ++m)
#pragma unroll
        for (int n = 0; n < 4; ++n) acc[m][n] = (f32x4){0.f, 0.f, 0.f, 0.f};

    for (int kt = 0; kt < 16; ++kt) {
        const int k0 = kt * 64;
#pragma unroll
        for (int it = 0; it < 4; ++it) {
            const int q = it * 256 + tid;       // 16B chunk id in [0,1024)
            const int r = q >> 3;               // tile row
            const int c = (q & 7) * 8;          // col (elems)
            gload_lds16(xb + (size_t)(m0 + r) * H_DIM + k0 + c, &As[(it * 4 + wid) * 512]);
            gload_lds16(wbf + (size_t)(n0 + r) * H_DIM + k0 + c, &Bs[(it * 4 + wid) * 512]);
        }
        __syncthreads();
#pragma unroll
        for (int kk = 0; kk < 64; kk += 32) {
            bf16x8 av[4], bv[4];
#pragma unroll
            for (int m = 0; m < 4; ++m)
                av[m] = *(const bf16x8*)&As[(wr * 64 + m * 16 + (lane & 15)) * 64 + kk + (lane >> 4) * 8];
#pragma unroll
            for (int n = 0; n < 4; ++n)
                bv[n] = *(const bf16x8*)&Bs[(wc * 64 + n * 16 + (lane & 15)) * 64 + kk + (lane >> 4) * 8];
#pragma unroll
            for (int m = 0; m < 4; ++m)
#pragma unroll
                for (int n = 0; n < 4; ++n)
                    acc[m][n] = __builtin_amdgcn_mfma_f32_16x16x32_bf16(av[m], bv[n], acc[m][n], 0, 0, 0);
        }
        __syncthreads();
    }

    const int crow = (lane >> 4) * 4;
    const int ccol = lane & 15;
#pragma unroll
    for (int m = 0; m < 4; ++m) {
#pragma unroll
        for (int n = 0; n < 4; ++n) {
            const int col = n0 + wc * 64 + n * 16 + ccol;
            const float bias = biascat[col];
#pragma unroll
            for (int r = 0; r < 4; ++r) {
                const int row = m0 + wr * 64 + m * 16 + crow + r;
                float v = acc[m][n][r] + bias;
                v = (col < 2432) ? gelu_erf(v) : fmaxf(v, 0.f);  // gelu for experts/shared/router, relu for value
                h1[(size_t)row * NBIG + col] = f2bf(v);
            }
        }
    }
}

// ---------------- router softmax + value rtg (reads H1 slices) ----------------

__global__ void k_router_value(const u16* __restrict__ h1,
                               const float* __restrict__ rw2, const float* __restrict__ rb2,
                               const float* __restrict__ vw2, const float* __restrict__ vb2,
                               float* __restrict__ probs_out, float* __restrict__ rtg_out) {
    __shared__ float rh[32][130];
    __shared__ float vh[32][130];
    __shared__ float w2[RH_DIM * E_NUM];
    __shared__ float vw[RH_DIM];
    const int tid = threadIdx.x;
    const int t0 = blockIdx.x * 32;
    for (int i = tid; i < RH_DIM * E_NUM; i += 256) w2[i] = rw2[i];
    if (tid < RH_DIM) vw[tid] = vw2[tid];
    {
        const int row = tid >> 3;
        const int c0 = (tid & 7) * 16;
        const u16* srcr = h1 + (size_t)(t0 + row) * NBIG + 2304 + c0;
        const u16* srcv = h1 + (size_t)(t0 + row) * NBIG + 2432 + c0;
        u16x8 a0 = *(const u16x8*)srcr;
        u16x8 a1 = *(const u16x8*)(srcr + 8);
        u16x8 b0 = *(const u16x8*)srcv;
        u16x8 b1 = *(const u16x8*)(srcv + 8);
#pragma unroll
        for (int j = 0; j < 8; ++j) {
            rh[row][c0 + j] = bf2f(a0[j]);
            rh[row][c0 + 8 + j] = bf2f(a1[j]);
            vh[row][c0 + j] = bf2f(b0[j]);
            vh[row][c0 + 8 + j] = bf2f(b1[j]);
        }
    }
    __syncthreads();
    const int tl = tid >> 3, a = tid & 7;
    float acc = rb2[a];
#pragma unroll 8
    for (int d = 0; d < RH_DIM; ++d) acc += rh[tl][d] * w2[d * E_NUM + a];
    float mx = acc;
    mx = fmaxf(mx, __shfl_xor(mx, 1));
    mx = fmaxf(mx, __shfl_xor(mx, 2));
    mx = fmaxf(mx, __shfl_xor(mx, 4));
    float ex = expf(acc - mx);
    float sm = ex;
    sm += __shfl_xor(sm, 1);
    sm += __shfl_xor(sm, 2);
    sm += __shfl_xor(sm, 4);
    probs_out[(size_t)(t0 + tl) * E_NUM + a] = ex / sm;
    // value head
    float pv = 0.f;
#pragma unroll
    for (int j = 0; j < 16; ++j) pv += vh[tl][a * 16 + j] * vw[a * 16 + j];
    pv += __shfl_xor(pv, 1);
    pv += __shfl_xor(pv, 2);
    pv += __shfl_xor(pv, 4);
    if (a == 0) rtg_out[t0 + tl] = 1.f / (1.f + expf(-(pv + vb2[0])));
}

// ---------------- GEMM2: prob-scaled H1[8192x2304] @ W2T^T -> weighted/moe [8192x32] ----------------

__launch_bounds__(256, 2)
__global__ void k_gemm2(const u16* __restrict__ h1, const u16* __restrict__ w2t,
                        const float* __restrict__ probs,
                        const float* __restrict__ eb2, const float* __restrict__ sb2,
                        float* __restrict__ moe_out, float* __restrict__ wgt_out) {
    __shared__ u16 As[128 * 64];
    __shared__ u16 Bs[32 * 64];
    const int tid = threadIdx.x;
    const int wid = tid >> 6;
    const int lane = tid & 63;
    const int m0 = blockIdx.x * 128;

    f32x4 accE[2][2], accS[2][2];
#pragma unroll
    for (int m = 0; m < 2; ++m)
#pragma unroll
        for (int n = 0; n < 2; ++n) {
            accE[m][n] = (f32x4){0.f, 0.f, 0.f, 0.f};
            accS[m][n] = (f32x4){0.f, 0.f, 0.f, 0.f};
        }

    for (int kt = 0; kt < 36; ++kt) {
        const int k0 = kt * 64;
#pragma unroll
        for (int it = 0; it < 4; ++it) {
            const int q = it * 256 + tid;
            const int r = q >> 3;
            const int c = (q & 7) * 8;
            u16x8 v = *(const u16x8*)(h1 + (size_t)(m0 + r) * NBIG + k0 + c);
            float scl = (kt < 32) ? probs[(size_t)(m0 + r) * E_NUM + (kt >> 2)] : 1.0f;
            u16x8 o;
#pragma unroll
            for (int j = 0; j < 8; ++j) o[j] = f2bf(bf2f(v[j]) * scl);
            *(u16x8*)&As[r * 64 + c] = o;
        }
        {
            const int r = tid >> 3;
            const int c = (tid & 7) * 8;
            *(u16x8*)&Bs[r * 64 + c] = *(const u16x8*)(w2t + (size_t)r * K2 + k0 + c);
        }
        __syncthreads();
#pragma unroll
        for (int kk = 0; kk < 64; kk += 32) {
            bf16x8 av[2], bv[2];
#pragma unroll
            for (int m = 0; m < 2; ++m)
                av[m] = *(const bf16x8*)&As[(wid * 32 + m * 16 + (lane & 15)) * 64 + kk + (lane >> 4) * 8];
#pragma unroll
            for (int n = 0; n < 2; ++n)
                bv[n] = *(const bf16x8*)&Bs[(n * 16 + (lane & 15)) * 64 + kk + (lane >> 4) * 8];
            if (kt < 32) {
#pragma unroll
                for (int m = 0; m < 2; ++m)
#pragma unroll
                    for (int n = 0; n < 2; ++n)
                        accE[m][n] = __builtin_amdgcn_mfma_f32_16x16x32_bf16(av[m], bv[n], accE[m][n], 0, 0, 0);
            } else {
#pragma unroll
                for (int m = 0; m < 2; ++m)
#pragma unroll
                    for (int n = 0; n < 2; ++n)
                        accS[m][n] = __builtin_amdgcn_mfma_f32_16x16x32_bf16(av[m], bv[n], accS[m][n], 0, 0, 0);
            }
        }
        __syncthreads();
    }

    const int crow = (lane >> 4) * 4;
    const int ccol = lane & 15;
#pragma unroll
    for (int m = 0; m < 2; ++m) {
#pragma unroll
        for (int n = 0; n < 2; ++n) {
            const int aIdx = n * 16 + ccol;
#pragma unroll
            for (int r = 0; r < 4; ++r) {
                const int t = m0 + wid * 32 + m * 16 + crow + r;
                const float* p = &probs[(size_t)t * E_NUM];
                float wb = 0.f;
#pragma unroll
                for (int e = 0; e < E_NUM; ++e) wb += p[e] * eb2[e * A_DIM + aIdx];
                const float w = accE[m][n][r] + wb;                 // weighted_expert
                const float mo = w + accS[m][n][r] + sb2[aIdx];     // + shared_output
                wgt_out[(size_t)t * A_DIM + aIdx] = w;
                moe_out[(size_t)t * A_DIM + aIdx] = mo;
            }
        }
    }
}

// ---------------- residual MLP + final combine ----------------

__global__ void k_final(const float* __restrict__ moe, const float* __restrict__ wgt,
                        const float* __restrict__ mw1, const float* __restrict__ mb1,
                        const float* __restrict__ mw2, const float* __restrict__ mb2,
                        const float* __restrict__ mask, float* __restrict__ outp) {
    __shared__ float w1[A_DIM * RH_DIM];
    __shared__ float w2[RH_DIM * A_DIM];
    __shared__ float mo[32][33];
    __shared__ float rh[32][128];
    const int tid = threadIdx.x;
    const int t0 = blockIdx.x * 32;
    for (int i = tid; i < A_DIM * RH_DIM; i += 1024) { w1[i] = mw1[i]; w2[i] = mw2[i]; }
    const int tl = tid >> 5, a = tid & 31;
    mo[tl][a] = moe[(size_t)(t0 + tl) * A_DIM + a];
    __syncthreads();
#pragma unroll
    for (int jj = 0; jj < 4; ++jj) {
        const int j = a * 4 + jj;
        float s = mb1[j];
#pragma unroll
        for (int aa = 0; aa < 32; ++aa) s += mo[tl][aa] * w1[aa * RH_DIM + j];
        rh[tl][j] = gelu_erf(s);
    }
    __syncthreads();
    float s = mb2[a];
#pragma unroll
    for (int j = 0; j < RH_DIM; ++j) s += rh[tl][j] * w2[j * A_DIM + a];
    const float res = wgt[(size_t)(t0 + tl) * A_DIM + a] + s;
    outp[(size_t)(t0 + tl) * A_DIM + a] = res * mask[t0 + tl];
}

// ---------------- launch ----------------

extern "C" void kernel_launch(void* const* d_in, const int* in_sizes, int n_in,
                              void* d_out, int out_size, void* d_ws, size_t ws_size,
                              hipStream_t stream) {
    const float* state = (const float*)d_in[0];
    const float* base  = (const float*)d_in[1];
    const float* mask  = (const float*)d_in[2];
    const float* sw1 = (const float*)d_in[3];
    const float* sb1 = (const float*)d_in[4];
    const float* sw2 = (const float*)d_in[5];
    const float* sb2 = (const float*)d_in[6];
    const float* ew1 = (const float*)d_in[7];
    const float* eb1 = (const float*)d_in[8];
    const float* ew2 = (const float*)d_in[9];
    const float* eb2 = (const float*)d_in[10];
    const float* rw1 = (const float*)d_in[11];
    const float* rb1 = (const float*)d_in[12];
    const float* rw2 = (const float*)d_in[13];
    const float* rb2 = (const float*)d_in[14];
    const float* mw1 = (const float*)d_in[15];
    const float* mb1 = (const float*)d_in[16];
    const float* mw2 = (const float*)d_in[17];
    const float* mb2 = (const float*)d_in[18];
    const float* vw1 = (const float*)d_in[19];
    const float* vb1 = (const float*)d_in[20];
    const float* vw2 = (const float*)d_in[21];
    const float* vb2 = (const float*)d_in[22];

    float* out_final = (float*)d_out;                 // [32768][32]
    float* out_cand  = out_final + 1048576;           // [32768][8][32]
    float* out_probs = out_final + 9437184;           // [32768][8]
    float* out_rtg   = out_final + 9699328;           // [32768]

    // workspace layout (~66 MB total)
    char* ws = (char*)d_ws;
    size_t off = 0;
    auto take = [&](size_t b) { char* p = ws + off; off += (b + 255) & ~(size_t)255; return p; };
    u16*   wbf   = (u16*)take((size_t)NBIG * H_DIM * 2);     // 5.24 MB
    u16*   w2t   = (u16*)take((size_t)A_DIM * K2 * 2);       // 147 KB
    float* bias  = (float*)take((size_t)NBIG * 4);           // 10 KB
    u16*   xb    = (u16*)take((size_t)CHUNK * H_DIM * 2);    // 16.8 MB
    u16*   h1    = (u16*)take((size_t)CHUNK * NBIG * 2);     // 41.9 MB
    float* moe   = (float*)take((size_t)CHUNK * A_DIM * 4);  // 1.05 MB
    float* wgt   = (float*)take((size_t)CHUNK * A_DIM * 4);  // 1.05 MB
    (void)ws_size; (void)in_sizes; (void)n_in; (void)out_size;

    k_pack_w<<<(NBIG * H_DIM) / 256, 256, 0, stream>>>(ew1, sw1, rw1, vw1, eb1, sb1, rb1, vb1, wbf, bias);
    k_pack_w2t<<<(A_DIM * K2) / 256, 256, 0, stream>>>(ew2, sw2, w2t);
    k_cand<<<(T_TOT * E_NUM * A_DIM) / 256, 256, 0, stream>>>(base, out_cand);

    for (int c = 0; c < NCHUNK; ++c) {
        const size_t tb = (size_t)c * CHUNK;
        k_convert_x<<<(CHUNK * H_DIM / 4) / 256, 256, 0, stream>>>(state + tb * H_DIM, xb, CHUNK * H_DIM / 4);
        k_gemm1<<<dim3(NBIG / 128, CHUNK / 128), 256, 0, stream>>>(xb, wbf, bias, h1);
        k_router_value<<<CHUNK / 32, 256, 0, stream>>>(h1, rw2, rb2, vw2, vb2,
                                                       out_probs + tb * E_NUM, out_rtg + tb);
        k_gemm2<<<CHUNK / 128, 256, 0, stream>>>(h1, w2t, out_probs + tb * E_NUM, eb2, sb2, moe, wgt);
        k_final<<<CHUNK / 32, 1024, 0, stream>>>(moe, wgt, mw1, mb1, mw2, mb2, mask + tb, out_final + tb * A_DIM);
    }
}

// Round 4
// 416.870 us; speedup vs baseline: 1.7908x; 1.7908x over previous
//
#include <hip/hip_runtime.h>
#include <stdint.h>

// Problem dims
#define T_TOT 32768   // B*S
#define H_DIM 1024
#define A_DIM 32
#define E_NUM 8
#define ED_DIM 256
#define RH_DIM 128
#define NBIG 2560     // 8*256 experts + 256 shared + 128 router + 128 value
#define K2 2304       // 8*256 + 256 (expert+shared h1 -> action)

typedef float f32x4 __attribute__((ext_vector_type(4)));
typedef short bf16x8 __attribute__((ext_vector_type(8)));
typedef unsigned short u16;
typedef u16 u16x8 __attribute__((ext_vector_type(8)));

typedef uint32_t __attribute__((address_space(1))) as1_u32;
typedef uint32_t __attribute__((address_space(3))) as3_u32;

__device__ __forceinline__ u16 f2bf(float f) {
    union { float f; uint32_t u; } v; v.f = f;
    return (u16)((v.u + 0x7FFFu + ((v.u >> 16) & 1u)) >> 16);  // RNE
}
__device__ __forceinline__ float bf2f(u16 h) {
    union { uint32_t u; float f; } v; v.u = ((uint32_t)h) << 16;
    return v.f;
}
__device__ __forceinline__ float gelu_erf(float x) {
    return 0.5f * x * (1.0f + erff(x * 0.70710678118654752f));
}
__device__ __forceinline__ void gload_lds16(const void* g, void* lds) {
    __builtin_amdgcn_global_load_lds((const as1_u32*)(uintptr_t)g,
                                     (as3_u32*)(uintptr_t)lds, 16, 0, 0);
}

// ---------------- setup kernels ----------------

__global__ void k_convert_x(const float* __restrict__ x, u16* __restrict__ xb, int n4) {
    int i = blockIdx.x * blockDim.x + threadIdx.x;
    if (i >= n4) return;
    float4 v = ((const float4*)x)[i];
    ushort4 o;
    o.x = f2bf(v.x); o.y = f2bf(v.y); o.z = f2bf(v.z); o.w = f2bf(v.w);
    ((ushort4*)xb)[i] = o;
}

// pack big W^T [NBIG][K=1024] bf16 + concatenated bias (fp32)
__global__ void k_pack_w(const float* __restrict__ ew1, const float* __restrict__ sw1,
                         const float* __restrict__ rw1, const float* __restrict__ vw1,
                         const float* __restrict__ eb1, const float* __restrict__ sb1,
                         const float* __restrict__ rb1, const float* __restrict__ vb1,
                         u16* __restrict__ wbf, float* __restrict__ biascat) {
    int t = blockIdx.x * blockDim.x + threadIdx.x;
    if (t >= NBIG * H_DIM) return;
    int n = t >> 10, k = t & 1023;
    float v;
    if (n < 2048)      v = ew1[(size_t)(((n >> 8) * H_DIM) + k) * ED_DIM + (n & 255)];
    else if (n < 2304) v = sw1[(size_t)k * ED_DIM + (n - 2048)];
    else if (n < 2432) v = rw1[(size_t)k * RH_DIM + (n - 2304)];
    else               v = vw1[(size_t)k * RH_DIM + (n - 2432)];
    wbf[t] = f2bf(v);
    if (k == 0) {
        float b;
        if (n < 2048)      b = eb1[(n >> 8) * ED_DIM + (n & 255)];
        else if (n < 2304) b = sb1[n - 2048];
        else if (n < 2432) b = rb1[n - 2304];
        else               b = vb1[n - 2432];
        biascat[n] = b;
    }
}

// pack second-layer weights transposed: W2T [32][2304] bf16 (expert | shared)
__global__ void k_pack_w2t(const float* __restrict__ ew2, const float* __restrict__ sw2,
                           u16* __restrict__ w2t) {
    int t = blockIdx.x * blockDim.x + threadIdx.x;
    if (t >= A_DIM * K2) return;
    int a = t / K2, d = t - a * K2;
    float v = (d < 2048) ? ew2[(size_t)d * A_DIM + a] : sw2[(size_t)(d - 2048) * A_DIM + a];
    w2t[t] = f2bf(v);
}

__global__ void k_cand(const float* __restrict__ base, float* __restrict__ outp) {
    int i = blockIdx.x * blockDim.x + threadIdx.x;
    if (i >= T_TOT * E_NUM * A_DIM) return;
    int a = i & 31, e = (i >> 5) & 7, t = i >> 8;
    outp[i] = base[(size_t)t * A_DIM + a] * (0.8f + 0.4f * (float)e / 7.0f);
}

// ---------------- GEMM1: X[Tx1024] @ Wbig -> H1[Tx2560] (act applied, bf16) ----------------
// 128x128 tile, BK=64, double-buffered LDS (stage-next-before-compute, one
// barrier per K-tile), T2 XOR swizzle: LDS slot (r, s) holds global slot
// s^(r&7); ds_read XORs the same term back (rule #21 involution).

__launch_bounds__(256, 2)
__global__ void k_gemm1(const u16* __restrict__ xb, const u16* __restrict__ wbf,
                        const float* __restrict__ biascat, u16* __restrict__ h1) {
    __shared__ u16 As[2][128 * 64];
    __shared__ u16 Bs[2][128 * 64];
    const int tid = threadIdx.x;
    const int wid = tid >> 6;
    const int lane = tid & 63;
    const int m0 = blockIdx.y * 128;
    const int n0 = blockIdx.x * 128;
    const int wr = wid >> 1, wc = wid & 1;
    // pre-swizzled source column (elems): slot (tid&7) in LDS gets global slot (tid&7)^(r&7)
    const int csrc = 8 * ((tid & 7) ^ ((tid >> 3) & 7));
    const int rxor = (lane & 7) * 8;      // read-side XOR (rowA&7)*8 == (lane&7)*8
    const int lhi8 = (lane >> 4) * 8;

    f32x4 acc[4][4];
#pragma unroll
    for (int m = 0; m < 4; ++m)
#pragma unroll
        for (int n = 0; n < 4; ++n) acc[m][n] = (f32x4){0.f, 0.f, 0.f, 0.f};

    auto stage = [&](int buf, int kt) {
        const int k0 = kt * 64;
#pragma unroll
        for (int it = 0; it < 4; ++it) {
            const int r = it * 32 + (tid >> 3);
            gload_lds16(xb + (size_t)(m0 + r) * H_DIM + k0 + csrc, &As[buf][(it * 4 + wid) * 512]);
            gload_lds16(wbf + (size_t)(n0 + r) * H_DIM + k0 + csrc, &Bs[buf][(it * 4 + wid) * 512]);
        }
    };
    auto comp = [&](int buf) {
#pragma unroll
        for (int kk = 0; kk < 64; kk += 32) {
            bf16x8 av[4], bv[4];
#pragma unroll
            for (int m = 0; m < 4; ++m)
                av[m] = *(const bf16x8*)&As[buf][(wr * 64 + m * 16 + (lane & 15)) * 64 + ((kk + lhi8) ^ rxor)];
#pragma unroll
            for (int n = 0; n < 4; ++n)
                bv[n] = *(const bf16x8*)&Bs[buf][(wc * 64 + n * 16 + (lane & 15)) * 64 + ((kk + lhi8) ^ rxor)];
#pragma unroll
            for (int m = 0; m < 4; ++m)
#pragma unroll
                for (int n = 0; n < 4; ++n)
                    acc[m][n] = __builtin_amdgcn_mfma_f32_16x16x32_bf16(av[m], bv[n], acc[m][n], 0, 0, 0);
        }
    };

    stage(0, 0);
    __syncthreads();
    int cur = 0;
    for (int kt = 0; kt < 16; ++kt) {
        if (kt < 15) stage(cur ^ 1, kt + 1);   // issue next-tile loads first (overlap)
        comp(cur);
        __syncthreads();                        // vmcnt(0)+barrier: next buf ready, cur reusable
        cur ^= 1;
    }

    const int crow = (lane >> 4) * 4;
    const int ccol = lane & 15;
#pragma unroll
    for (int m = 0; m < 4; ++m) {
#pragma unroll
        for (int n = 0; n < 4; ++n) {
            const int col = n0 + wc * 64 + n * 16 + ccol;
            const float bias = biascat[col];
#pragma unroll
            for (int r = 0; r < 4; ++r) {
                const int row = m0 + wr * 64 + m * 16 + crow + r;
                float v = acc[m][n][r] + bias;
                v = (col < 2432) ? gelu_erf(v) : fmaxf(v, 0.f);  // gelu experts/shared/router, relu value
                h1[(size_t)row * NBIG + col] = f2bf(v);
            }
        }
    }
}

// ---------------- router softmax + value rtg ----------------

__global__ void k_router_value(const u16* __restrict__ h1,
                               const float* __restrict__ rw2, const float* __restrict__ rb2,
                               const float* __restrict__ vw2, const float* __restrict__ vb2,
                               float* __restrict__ probs_out, float* __restrict__ rtg_out) {
    __shared__ float rh[32][130];
    __shared__ float vh[32][130];
    __shared__ float w2[RH_DIM * E_NUM];
    __shared__ float vw[RH_DIM];
    const int tid = threadIdx.x;
    const int t0 = blockIdx.x * 32;
    for (int i = tid; i < RH_DIM * E_NUM; i += 256) w2[i] = rw2[i];
    if (tid < RH_DIM) vw[tid] = vw2[tid];
    {
        const int row = tid >> 3;
        const int c0 = (tid & 7) * 16;
        const u16* srcr = h1 + (size_t)(t0 + row) * NBIG + 2304 + c0;
        const u16* srcv = h1 + (size_t)(t0 + row) * NBIG + 2432 + c0;
        u16x8 a0 = *(const u16x8*)srcr;
        u16x8 a1 = *(const u16x8*)(srcr + 8);
        u16x8 b0 = *(const u16x8*)srcv;
        u16x8 b1 = *(const u16x8*)(srcv + 8);
#pragma unroll
        for (int j = 0; j < 8; ++j) {
            rh[row][c0 + j] = bf2f(a0[j]);
            rh[row][c0 + 8 + j] = bf2f(a1[j]);
            vh[row][c0 + j] = bf2f(b0[j]);
            vh[row][c0 + 8 + j] = bf2f(b1[j]);
        }
    }
    __syncthreads();
    const int tl = tid >> 3, a = tid & 7;
    float acc = rb2[a];
#pragma unroll 8
    for (int d = 0; d < RH_DIM; ++d) acc += rh[tl][d] * w2[d * E_NUM + a];
    float mx = acc;
    mx = fmaxf(mx, __shfl_xor(mx, 1));
    mx = fmaxf(mx, __shfl_xor(mx, 2));
    mx = fmaxf(mx, __shfl_xor(mx, 4));
    float ex = expf(acc - mx);
    float sm = ex;
    sm += __shfl_xor(sm, 1);
    sm += __shfl_xor(sm, 2);
    sm += __shfl_xor(sm, 4);
    probs_out[(size_t)(t0 + tl) * E_NUM + a] = ex / sm;
    float pv = 0.f;
#pragma unroll
    for (int j = 0; j < 16; ++j) pv += vh[tl][a * 16 + j] * vw[a * 16 + j];
    pv += __shfl_xor(pv, 1);
    pv += __shfl_xor(pv, 2);
    pv += __shfl_xor(pv, 4);
    if (a == 0) rtg_out[t0 + tl] = 1.f / (1.f + expf(-(pv + vb2[0])));
}

// ---------------- GEMM2: H1[Tx2304] @ W2T^T with per-expert prob fold -> weighted/moe ----------------
// Expert e owns K-tiles 4e..4e+3; unscaled partial acc is folded into accT
// with prob p[t][e] (f32) after each expert. gload_lds staging + T2 swizzle.

__launch_bounds__(256, 2)
__global__ void k_gemm2(const u16* __restrict__ h1, const u16* __restrict__ w2t,
                        const float* __restrict__ probs,
                        const float* __restrict__ eb2, const float* __restrict__ sb2,
                        float* __restrict__ moe_out, float* __restrict__ wgt_out) {
    __shared__ u16 As[2][128 * 64];
    __shared__ u16 Bs[2][32 * 64];
    __shared__ float plds[128 * E_NUM];
    const int tid = threadIdx.x;
    const int wid = tid >> 6;
    const int lane = tid & 63;
    const int m0 = blockIdx.x * 128;
    const int csrc = 8 * ((tid & 7) ^ ((tid >> 3) & 7));
    const int rxor = (lane & 7) * 8;
    const int lhi8 = (lane >> 4) * 8;
    const int crow = (lane >> 4) * 4;
    const int ccol = lane & 15;

    for (int i = tid; i < 128 * E_NUM; i += 256) plds[i] = probs[(size_t)m0 * E_NUM + i];

    f32x4 acc[2][2], accT[2][2], accS[2][2];
#pragma unroll
    for (int m = 0; m < 2; ++m)
#pragma unroll
        for (int n = 0; n < 2; ++n) {
            acc[m][n] = (f32x4){0.f, 0.f, 0.f, 0.f};
            accT[m][n] = (f32x4){0.f, 0.f, 0.f, 0.f};
            accS[m][n] = (f32x4){0.f, 0.f, 0.f, 0.f};
        }

    auto stage = [&](int buf, int kt) {
        const int k0 = kt * 64;
#pragma unroll
        for (int it = 0; it < 4; ++it) {
            const int r = it * 32 + (tid >> 3);
            gload_lds16(h1 + (size_t)(m0 + r) * NBIG + k0 + csrc, &As[buf][(it * 4 + wid) * 512]);
        }
        // B tile: 32 rows x 64 cols = 4KB, one 16B chunk per thread
        gload_lds16(w2t + (size_t)(tid >> 3) * K2 + k0 + csrc, &Bs[buf][wid * 512]);
    };

    stage(0, 0);
    __syncthreads();
    int cur = 0;
    for (int kt = 0; kt < 36; ++kt) {
        if (kt < 35) stage(cur ^ 1, kt + 1);
        const bool isExp = (kt < 32);
#pragma unroll
        for (int kk = 0; kk < 64; kk += 32) {
            bf16x8 av[2], bv[2];
#pragma unroll
            for (int m = 0; m < 2; ++m)
                av[m] = *(const bf16x8*)&As[cur][(wid * 32 + m * 16 + (lane & 15)) * 64 + ((kk + lhi8) ^ rxor)];
#pragma unroll
            for (int n = 0; n < 2; ++n)
                bv[n] = *(const bf16x8*)&Bs[cur][(n * 16 + (lane & 15)) * 64 + ((kk + lhi8) ^ rxor)];
            if (isExp) {
#pragma unroll
                for (int m = 0; m < 2; ++m)
#pragma unroll
                    for (int n = 0; n < 2; ++n)
                        acc[m][n] = __builtin_amdgcn_mfma_f32_16x16x32_bf16(av[m], bv[n], acc[m][n], 0, 0, 0);
            } else {
#pragma unroll
                for (int m = 0; m < 2; ++m)
#pragma unroll
                    for (int n = 0; n < 2; ++n)
                        accS[m][n] = __builtin_amdgcn_mfma_f32_16x16x32_bf16(av[m], bv[n], accS[m][n], 0, 0, 0);
            }
        }
        if (isExp && (kt & 3) == 3) {
            const int e = kt >> 2;
#pragma unroll
            for (int m = 0; m < 2; ++m)
#pragma unroll
                for (int r = 0; r < 4; ++r) {
                    const float p = plds[(wid * 32 + m * 16 + crow + r) * E_NUM + e];
#pragma unroll
                    for (int n = 0; n < 2; ++n) {
                        accT[m][n][r] += p * acc[m][n][r];
                        acc[m][n][r] = 0.f;
                    }
                }
        }
        __syncthreads();
        cur ^= 1;
    }

#pragma unroll
    for (int m = 0; m < 2; ++m) {
#pragma unroll
        for (int n = 0; n < 2; ++n) {
            const int aIdx = n * 16 + ccol;
#pragma unroll
            for (int r = 0; r < 4; ++r) {
                const int row = wid * 32 + m * 16 + crow + r;
                const int t = m0 + row;
                float wb = 0.f;
#pragma unroll
                for (int e = 0; e < E_NUM; ++e) wb += plds[row * E_NUM + e] * eb2[e * A_DIM + aIdx];
                const float w = accT[m][n][r] + wb;               // weighted_expert
                const float mo = w + accS[m][n][r] + sb2[aIdx];   // + shared_output
                wgt_out[(size_t)t * A_DIM + aIdx] = w;
                moe_out[(size_t)t * A_DIM + aIdx] = mo;
            }
        }
    }
}

// ---------------- residual MLP + final combine ----------------

__global__ void k_final(const float* __restrict__ moe, const float* __restrict__ wgt,
                        const float* __restrict__ mw1, const float* __restrict__ mb1,
                        const float* __restrict__ mw2, const float* __restrict__ mb2,
                        const float* __restrict__ mask, float* __restrict__ outp) {
    __shared__ float w1[A_DIM * RH_DIM];
    __shared__ float w2[RH_DIM * A_DIM];
    __shared__ float mo[32][33];
    __shared__ float rh[32][128];
    const int tid = threadIdx.x;
    const int t0 = blockIdx.x * 32;
    for (int i = tid; i < A_DIM * RH_DIM; i += 1024) { w1[i] = mw1[i]; w2[i] = mw2[i]; }
    const int tl = tid >> 5, a = tid & 31;
    mo[tl][a] = moe[(size_t)(t0 + tl) * A_DIM + a];
    __syncthreads();
#pragma unroll
    for (int jj = 0; jj < 4; ++jj) {
        const int j = a * 4 + jj;
        float s = mb1[j];
#pragma unroll
        for (int aa = 0; aa < 32; ++aa) s += mo[tl][aa] * w1[aa * RH_DIM + j];
        rh[tl][j] = gelu_erf(s);
    }
    __syncthreads();
    float s = mb2[a];
#pragma unroll
    for (int j = 0; j < RH_DIM; ++j) s += rh[tl][j] * w2[j * A_DIM + a];
    const float res = wgt[(size_t)(t0 + tl) * A_DIM + a] + s;
    outp[(size_t)(t0 + tl) * A_DIM + a] = res * mask[t0 + tl];
}

// ---------------- launch ----------------

extern "C" void kernel_launch(void* const* d_in, const int* in_sizes, int n_in,
                              void* d_out, int out_size, void* d_ws, size_t ws_size,
                              hipStream_t stream) {
    const float* state = (const float*)d_in[0];
    const float* base  = (const float*)d_in[1];
    const float* mask  = (const float*)d_in[2];
    const float* sw1 = (const float*)d_in[3];
    const float* sb1 = (const float*)d_in[4];
    const float* sw2 = (const float*)d_in[5];
    const float* sb2 = (const float*)d_in[6];
    const float* ew1 = (const float*)d_in[7];
    const float* eb1 = (const float*)d_in[8];
    const float* ew2 = (const float*)d_in[9];
    const float* eb2 = (const float*)d_in[10];
    const float* rw1 = (const float*)d_in[11];
    const float* rb1 = (const float*)d_in[12];
    const float* rw2 = (const float*)d_in[13];
    const float* rb2 = (const float*)d_in[14];
    const float* mw1 = (const float*)d_in[15];
    const float* mb1 = (const float*)d_in[16];
    const float* mw2 = (const float*)d_in[17];
    const float* mb2 = (const float*)d_in[18];
    const float* vw1 = (const float*)d_in[19];
    const float* vb1 = (const float*)d_in[20];
    const float* vw2 = (const float*)d_in[21];
    const float* vb2 = (const float*)d_in[22];

    float* out_final = (float*)d_out;                 // [32768][32]
    float* out_cand  = out_final + 1048576;           // [32768][8][32]
    float* out_probs = out_final + 9437184;           // [32768][8]
    float* out_rtg   = out_final + 9699328;           // [32768]

    // adaptive chunking: largest chunk whose ws footprint fits (deterministic in ws_size)
    auto al = [](size_t b) { return (b + 255) & ~(size_t)255; };
    auto need = [&](size_t T) {
        return al((size_t)NBIG * H_DIM * 2) + al((size_t)A_DIM * K2 * 2) + al((size_t)NBIG * 4)
             + al(T * H_DIM * 2) + al(T * NBIG * 2) + 2 * al(T * A_DIM * 4);
    };
    size_t Tc = 8192;
    if (need(32768) <= ws_size)      Tc = 32768;
    else if (need(16384) <= ws_size) Tc = 16384;
    const int nchunk = (int)(T_TOT / Tc);

    char* ws = (char*)d_ws;
    size_t off = 0;
    auto take = [&](size_t b) { char* p = ws + off; off += (b + 255) & ~(size_t)255; return p; };
    u16*   wbf   = (u16*)take((size_t)NBIG * H_DIM * 2);
    u16*   w2t   = (u16*)take((size_t)A_DIM * K2 * 2);
    float* bias  = (float*)take((size_t)NBIG * 4);
    u16*   xb    = (u16*)take(Tc * H_DIM * 2);
    u16*   h1    = (u16*)take(Tc * NBIG * 2);
    float* moe   = (float*)take(Tc * A_DIM * 4);
    float* wgt   = (float*)take(Tc * A_DIM * 4);
    (void)in_sizes; (void)n_in; (void)out_size;

    k_pack_w<<<(NBIG * H_DIM) / 256, 256, 0, stream>>>(ew1, sw1, rw1, vw1, eb1, sb1, rb1, vb1, wbf, bias);
    k_pack_w2t<<<(A_DIM * K2) / 256, 256, 0, stream>>>(ew2, sw2, w2t);
    k_cand<<<(T_TOT * E_NUM * A_DIM) / 256, 256, 0, stream>>>(base, out_cand);

    for (int c = 0; c < nchunk; ++c) {
        const size_t tb = (size_t)c * Tc;
        k_convert_x<<<(int)(Tc * H_DIM / 4 / 256), 256, 0, stream>>>(state + tb * H_DIM, xb, (int)(Tc * H_DIM / 4));
        k_gemm1<<<dim3(NBIG / 128, (int)(Tc / 128)), 256, 0, stream>>>(xb, wbf, bias, h1);
        k_router_value<<<(int)(Tc / 32), 256, 0, stream>>>(h1, rw2, rb2, vw2, vb2,
                                                           out_probs + tb * E_NUM, out_rtg + tb);
        k_gemm2<<<(int)(Tc / 128), 256, 0, stream>>>(h1, w2t, out_probs + tb * E_NUM, eb2, sb2, moe, wgt);
        k_final<<<(int)(Tc / 32), 1024, 0, stream>>>(moe, wgt, mw1, mb1, mw2, mb2, mask + tb, out_final + tb * A_DIM);
    }
}